// Round 1
// baseline (1004.154 us; speedup 1.0000x reference)
//
#include <hip/hip_runtime.h>
#include <cstddef>

// FNO spectral conv: B=8, C_in=C_out=128, H=W=256, modes 64x64.
// Pipeline: fwd (truncated rfft2 per (b,i)) -> mix (per-mode complex channel GEMM)
//           -> inv (zero-padded irfft2 per (b,o)).
// All twiddles via per-thread complex rotator recurrences (no tables).

#define TWO_PI 6.28318530717958647692f

static constexpr int NB = 8, NC = 128, NH = 256, NW = 256, NM = 64;

// ---------------------------------------------------------------------------
// FWD: one block per (b*128+i). Computes Y[bi][kx][ky] (64x64 complex),
// Y = sum_h sum_w x[h][w] e^{-2pi i(h kx + w ky)/256}, kx,ky < 64 (unnormalized).
// ---------------------------------------------------------------------------
__global__ __launch_bounds__(256, 2) void fwd_kernel(const float* __restrict__ x,
                                                     float2* __restrict__ Y) {
    const int bi  = blockIdx.x;          // b*128+i
    const int tid = threadIdx.x;

    __shared__ float xs[32][260];        // 32 rows of x, padded (16B-aligned rows)
    __shared__ float Tre[32][68];        // T[h][ky] for current h-chunk
    __shared__ float Tim[32][68];

    // stage-2 geometry: rows r0=(tid>>4)*2 (+1), ky quad = (tid&15)*4
    const int s2_hg  = tid >> 4;
    const int s2_kyg = tid & 15;
    float s2c[4], s2s[4];
#pragma unroll
    for (int c = 0; c < 4; ++c) {
        float ang = TWO_PI * (float)(s2_kyg * 4 + c) * (1.0f / 256.0f);
        s2c[c] = cosf(ang);
        s2s[c] = -sinf(ang);             // step = e^{-2pi i ky/256}
    }
    // stage-3 geometry: kx quad = (tid>>4)*4, ky quad = (tid&15)*4
    const int s3_kxg = tid >> 4;
    const int s3_kyg = tid & 15;
    float st3c[4], st3s[4], r3c[4], r3s[4];
#pragma unroll
    for (int a = 0; a < 4; ++a) {
        float ang = TWO_PI * (float)(s3_kxg * 4 + a) * (1.0f / 256.0f);
        st3c[a] = cosf(ang);
        st3s[a] = -sinf(ang);            // step = e^{-2pi i kx/256}
        r3c[a] = 1.0f; r3s[a] = 0.0f;    // rotator over h, persists across chunks
    }
    float Yre[4][4] = {{0.f}}, Yim[4][4] = {{0.f}};

    const float* xb = x + (size_t)bi * (NH * NW);

    for (int hc = 0; hc < 8; ++hc) {
        // ---- stage 1: load 32 rows into LDS (coalesced float4) ----
#pragma unroll
        for (int s = 0; s < 8; ++s) {
            int idx = tid + s * 256;
            int r = idx >> 6, c4 = idx & 63;
            float4 v = *(const float4*)(xb + (size_t)(hc * 32 + r) * NW + c4 * 4);
            *(float4*)&xs[r][c4 * 4] = v;
        }
        __syncthreads();

        // ---- stage 2: T[h][ky] = sum_w x[h][w] e^{-2pi i w ky/256} ----
        {
            float ar0[4] = {0,0,0,0}, ai0[4] = {0,0,0,0};
            float ar1[4] = {0,0,0,0}, ai1[4] = {0,0,0,0};
            float rc[4] = {1,1,1,1},  rs[4] = {0,0,0,0};
            const float* row0 = &xs[s2_hg * 2][0];
            const float* row1 = &xs[s2_hg * 2 + 1][0];
#pragma unroll 2
            for (int w = 0; w < 256; w += 2) {
                float2 a2 = *(const float2*)(row0 + w);
                float2 b2 = *(const float2*)(row1 + w);
#pragma unroll
                for (int u = 0; u < 2; ++u) {
                    float xa = u ? a2.y : a2.x;
                    float xv = u ? b2.y : b2.x;
#pragma unroll
                    for (int c = 0; c < 4; ++c) {
                        ar0[c] = fmaf(xa, rc[c], ar0[c]);
                        ai0[c] = fmaf(xa, rs[c], ai0[c]);
                        ar1[c] = fmaf(xv, rc[c], ar1[c]);
                        ai1[c] = fmaf(xv, rs[c], ai1[c]);
                        float nc = fmaf(rc[c], s2c[c], -rs[c] * s2s[c]);
                        float ns = fmaf(rc[c], s2s[c],  rs[c] * s2c[c]);
                        rc[c] = nc; rs[c] = ns;
                    }
                }
            }
            *(float4*)&Tre[s2_hg*2  ][s2_kyg*4] = make_float4(ar0[0], ar0[1], ar0[2], ar0[3]);
            *(float4*)&Tim[s2_hg*2  ][s2_kyg*4] = make_float4(ai0[0], ai0[1], ai0[2], ai0[3]);
            *(float4*)&Tre[s2_hg*2+1][s2_kyg*4] = make_float4(ar1[0], ar1[1], ar1[2], ar1[3]);
            *(float4*)&Tim[s2_hg*2+1][s2_kyg*4] = make_float4(ai1[0], ai1[1], ai1[2], ai1[3]);
        }
        __syncthreads();

        // ---- stage 3: Y[kx][ky] += sum_h e^{-2pi i h kx/256} * T[h][ky] ----
#pragma unroll 4
        for (int hh = 0; hh < 32; ++hh) {
            float4 tr4 = *(const float4*)&Tre[hh][s3_kyg * 4];
            float4 ti4 = *(const float4*)&Tim[hh][s3_kyg * 4];
            float tr[4] = {tr4.x, tr4.y, tr4.z, tr4.w};
            float ti[4] = {ti4.x, ti4.y, ti4.z, ti4.w};
#pragma unroll
            for (int a = 0; a < 4; ++a) {
#pragma unroll
                for (int c = 0; c < 4; ++c) {
                    Yre[a][c] = fmaf(r3c[a], tr[c], fmaf(-r3s[a], ti[c], Yre[a][c]));
                    Yim[a][c] = fmaf(r3c[a], ti[c], fmaf( r3s[a], tr[c], Yim[a][c]));
                }
                float nc = fmaf(r3c[a], st3c[a], -r3s[a] * st3s[a]);
                float ns = fmaf(r3c[a], st3s[a],  r3s[a] * st3c[a]);
                r3c[a] = nc; r3s[a] = ns;
            }
        }
        __syncthreads();   // protects xs/T overwrite next chunk (all readers done)
    }

    float2* yo = Y + (size_t)bi * (NM * NM);
#pragma unroll
    for (int a = 0; a < 4; ++a) {
        int kx = s3_kxg * 4 + a;
#pragma unroll
        for (int cc = 0; cc < 2; ++cc) {
            int c0 = cc * 2;
            *(float4*)(yo + (size_t)kx * NM + s3_kyg * 4 + c0) =
                make_float4(Yre[a][c0], Yim[a][c0], Yre[a][c0+1], Yim[a][c0+1]);
        }
    }
}

// ---------------------------------------------------------------------------
// MIX: one block per (kx, ky-octet). mixed[b,o,m] = sum_i Y[b,i,m] * W[i,o,m].
// Weight reads are fully coalesced (8 consecutive ky modes = 64B line).
// ---------------------------------------------------------------------------
__global__ __launch_bounds__(256) void mix_kernel(const float2* __restrict__ Y,
                                                  const float* __restrict__ Wg,
                                                  float2* __restrict__ Mx) {
    const int kx    = blockIdx.x >> 3;
    const int kyo   = blockIdx.x & 7;
    const int tid   = threadIdx.x;
    const int kxky0 = kx * 64 + kyo * 8;

    __shared__ float2 Ys[128 * 64];      // [i][b][j] : idx = i*64 + b*8 + j  (64 KB)

#pragma unroll
    for (int s = 0; s < 32; ++s) {
        int n = tid + s * 256;           // 0..8191
        int b = n >> 10, i = (n >> 3) & 127, j = n & 7;
        Ys[i * 64 + b * 8 + j] = Y[(size_t)(b * 128 + i) * 4096 + kxky0 + j];
    }
    __syncthreads();

    const int o  = tid >> 1;             // 0..127
    const int jh = tid & 1;              // which half of the 8 modes

    float accre[8][4] = {{0.f}}, accim[8][4] = {{0.f}};

    const float* wp = Wg + ((size_t)o * 4096 + kxky0 + jh * 4) * 2;
    const size_t istride = (size_t)128 * 4096 * 2;

    for (int i = 0; i < 128; ++i) {
        float4 wa = *(const float4*)(wp + (size_t)i * istride);
        float4 wb = *(const float4*)(wp + (size_t)i * istride + 4);
#pragma unroll
        for (int b = 0; b < 8; ++b) {
            float4 y01 = *(const float4*)&Ys[i * 64 + b * 8 + jh * 4];
            float4 y23 = *(const float4*)&Ys[i * 64 + b * 8 + jh * 4 + 2];
            accre[b][0] = fmaf(y01.x, wa.x, fmaf(-y01.y, wa.y, accre[b][0]));
            accim[b][0] = fmaf(y01.x, wa.y, fmaf( y01.y, wa.x, accim[b][0]));
            accre[b][1] = fmaf(y01.z, wa.z, fmaf(-y01.w, wa.w, accre[b][1]));
            accim[b][1] = fmaf(y01.z, wa.w, fmaf( y01.w, wa.z, accim[b][1]));
            accre[b][2] = fmaf(y23.x, wb.x, fmaf(-y23.y, wb.y, accre[b][2]));
            accim[b][2] = fmaf(y23.x, wb.y, fmaf( y23.y, wb.x, accim[b][2]));
            accre[b][3] = fmaf(y23.z, wb.z, fmaf(-y23.w, wb.w, accre[b][3]));
            accim[b][3] = fmaf(y23.z, wb.w, fmaf( y23.w, wb.z, accim[b][3]));
        }
    }
#pragma unroll
    for (int b = 0; b < 8; ++b) {
        float2* mo = Mx + (size_t)(b * 128 + o) * 4096 + kxky0 + jh * 4;
        *(float4*)(mo)     = make_float4(accre[b][0], accim[b][0], accre[b][1], accim[b][1]);
        *(float4*)(mo + 2) = make_float4(accre[b][2], accim[b][2], accre[b][3], accim[b][3]);
    }
}

// ---------------------------------------------------------------------------
// INV: one block per (b*128+o, h-chunk of 32). Zero-padded irfft2 from 64x64
// modes. C1: ifft along H (complex, 64 nonzero bins). C2: irfft along W
// (Hermitian: ky=0 weight 1 [Re only, matches numpy c2r], ky>=1 weight 2).
// Total ortho scale 1/65536 folded into C1 store.
// ---------------------------------------------------------------------------
__global__ __launch_bounds__(256, 2) void inv_kernel(const float2* __restrict__ Mx,
                                                     float* __restrict__ out) {
    const int blk  = blockIdx.x;
    const int pair = blk >> 3;           // b*128+o
    const int hc   = blk & 7;
    const int tid  = threadIdx.x;

    __shared__ float Mre[64][68], Mim[64][68];
    __shared__ float Ure[32][65], Uim[32][65];

#pragma unroll
    for (int s = 0; s < 16; ++s) {
        int n = tid + s * 256;           // 0..4095
        int kx = n >> 6, ky = n & 63;
        float2 v = Mx[(size_t)pair * 4096 + n];
        Mre[kx][ky] = v.x;
        Mim[kx][ky] = v.y;
    }
    __syncthreads();

    // ---- C1: U[h][ky] = sum_kx M[kx][ky] e^{+2pi i h kx/256} ----
    {
        const int hg  = tid >> 4;        // rows hloc = hg*2 + {0,1}
        const int kyg = tid & 15;        // ky = kyg*4 + c
        float stc[2], sts[2], rcc[2], rss[2];
#pragma unroll
        for (int rr = 0; rr < 2; ++rr) {
            int hglob = hc * 32 + hg * 2 + rr;
            float ang = TWO_PI * (float)hglob * (1.0f / 256.0f);
            stc[rr] = cosf(ang);
            sts[rr] = sinf(ang);         // positive exponent
            rcc[rr] = 1.0f; rss[rr] = 0.0f;
        }
        float ur[2][4] = {{0.f}}, ui[2][4] = {{0.f}};
#pragma unroll 4
        for (int kx = 0; kx < 64; ++kx) {
            float4 m4r = *(const float4*)&Mre[kx][kyg * 4];
            float4 m4i = *(const float4*)&Mim[kx][kyg * 4];
            float mre[4] = {m4r.x, m4r.y, m4r.z, m4r.w};
            float mim[4] = {m4i.x, m4i.y, m4i.z, m4i.w};
#pragma unroll
            for (int rr = 0; rr < 2; ++rr) {
#pragma unroll
                for (int c = 0; c < 4; ++c) {
                    ur[rr][c] = fmaf(rcc[rr], mre[c], fmaf(-rss[rr], mim[c], ur[rr][c]));
                    ui[rr][c] = fmaf(rcc[rr], mim[c], fmaf( rss[rr], mre[c], ui[rr][c]));
                }
                float nc = fmaf(rcc[rr], stc[rr], -rss[rr] * sts[rr]);
                float ns = fmaf(rcc[rr], sts[rr],  rss[rr] * stc[rr]);
                rcc[rr] = nc; rss[rr] = ns;
            }
        }
        const float inv_n = 1.0f / 65536.0f;
#pragma unroll
        for (int rr = 0; rr < 2; ++rr)
#pragma unroll
            for (int c = 0; c < 4; ++c) {
                int ky = kyg * 4 + c;
                float scl = (ky == 0) ? inv_n : (2.0f * inv_n);
                Ure[hg * 2 + rr][ky] = ur[rr][c] * scl;
                Uim[hg * 2 + rr][ky] = ui[rr][c] * scl;
            }
    }
    __syncthreads();

    // ---- C2: out[h][w] = sum_ky (Ur*cos - Ui*sin)(2pi w ky/256) ----
    {
        const int hg = tid >> 5;         // h = hg*4 + a   (8 groups * 4 = 32 rows)
        const int wg = tid & 31;         // w = wg*8 + ww
        float rc[8], rs[8], sc[8], ss[8];
#pragma unroll
        for (int ww = 0; ww < 8; ++ww) {
            float ang = TWO_PI * (float)(wg * 8 + ww) * (1.0f / 256.0f);
            sc[ww] = cosf(ang);
            ss[ww] = sinf(ang);
            rc[ww] = 1.0f; rs[ww] = 0.0f;
        }
        float acc[4][8] = {{0.f}};
#pragma unroll 2
        for (int ky = 0; ky < 64; ++ky) {
            float ur[4], ui[4];
#pragma unroll
            for (int a = 0; a < 4; ++a) {
                ur[a] = Ure[hg * 4 + a][ky];
                ui[a] = Uim[hg * 4 + a][ky];
            }
#pragma unroll
            for (int ww = 0; ww < 8; ++ww) {
#pragma unroll
                for (int a = 0; a < 4; ++a)
                    acc[a][ww] = fmaf(ur[a], rc[ww], fmaf(-ui[a], rs[ww], acc[a][ww]));
                float nc = fmaf(rc[ww], sc[ww], -rs[ww] * ss[ww]);
                float ns = fmaf(rc[ww], ss[ww],  rs[ww] * sc[ww]);
                rc[ww] = nc; rs[ww] = ns;
            }
        }
        float* ob = out + (size_t)pair * (NH * NW) + (size_t)(hc * 32) * NW;
#pragma unroll
        for (int a = 0; a < 4; ++a) {
            float* orow = ob + (size_t)(hg * 4 + a) * NW + wg * 8;
            *(float4*)(orow)     = make_float4(acc[a][0], acc[a][1], acc[a][2], acc[a][3]);
            *(float4*)(orow + 4) = make_float4(acc[a][4], acc[a][5], acc[a][6], acc[a][7]);
        }
    }
}

// ---------------------------------------------------------------------------
extern "C" void kernel_launch(void* const* d_in, const int* in_sizes, int n_in,
                              void* d_out, int out_size, void* d_ws, size_t ws_size,
                              hipStream_t stream) {
    (void)in_sizes; (void)n_in; (void)out_size; (void)ws_size;
    const float* x  = (const float*)d_in[0];
    const float* wg = (const float*)d_in[1];
    float* outp = (float*)d_out;

    float2* Y  = (float2*)d_ws;                                   // 33.55 MB
    float2* Mx = (float2*)((char*)d_ws + (size_t)NB * NC * NM * NM * sizeof(float2));

    fwd_kernel<<<NB * NC, 256, 0, stream>>>(x, Y);
    mix_kernel<<<NM * 8, 256, 0, stream>>>(Y, wg, Mx);
    inv_kernel<<<NB * NC * 8, 256, 0, stream>>>(Mx, outp);
}

// Round 2
// 659.294 us; speedup vs baseline: 1.5231x; 1.5231x over previous
//
#include <hip/hip_runtime.h>
#include <cstddef>

// FNO spectral conv, symmetry-folded fp32 pipeline:
//   F1: per-row truncated DFT along w with w<->256-w fold (real input)
//   F2: DFT along h with h<->256-h pair fold (complex T)
//   mix: per-mode complex channel GEMM (in-place Y -> M)
//   I1: inverse DFT along h writing both mirror rows from shared sums
//   I2: inverse DFT along w writing w and 256-w from even/odd parts
// All twiddles via <=128-step complex rotators (fp32, drift ~1e-6).

#define TWO_PI 6.28318530717958647692f

static constexpr int NB = 8, NC = 128;

// ---------------------------------------------------------------------------
// F1: block = (bil, h-chunk of 32). Tc[h][ky] = sum_wp E[wp]cos(t wp ky) + (-1)^ky x128
//     Ts[h][ky] = sum_wp O[wp]sin(t wp ky);  T = Tc - i Ts (wp in [0,128), t=2pi/256)
// ---------------------------------------------------------------------------
__global__ __launch_bounds__(256, 4) void f1_kernel(const float* __restrict__ x,
                                                    float* __restrict__ Tc_g,
                                                    float* __restrict__ Ts_g) {
    const int bil = blockIdx.x >> 3;
    const int hc  = blockIdx.x & 7;
    const int tid = threadIdx.x;

    __shared__ float Et[128][36];   // [wp][row], 36 keeps 16B alignment for 8-row reads
    __shared__ float Ot[128][36];
    __shared__ float x128s[32];

    const float* xb = x + (size_t)bil * 65536 + (size_t)hc * 32 * 256;

    // stage 1: build E/O transposed (direct from global; mirror via scalar loads)
#pragma unroll
    for (int k = 0; k < 4; ++k) {
        const int wq = (tid & 7) + k * 8;    // 0..31 (wp quads)
        const int r  = tid >> 3;             // 0..31
        float4 v = *(const float4*)(xb + r * 256 + wq * 4);
        float vv[4] = {v.x, v.y, v.z, v.w};
        float mv[4];
#pragma unroll
        for (int j = 0; j < 4; ++j) {
            int wp = wq * 4 + j;
            mv[j] = (wp == 0) ? 0.0f : xb[r * 256 + 256 - wp];
        }
#pragma unroll
        for (int j = 0; j < 4; ++j) {
            Et[wq * 4 + j][r] = vv[j] + mv[j];
            Ot[wq * 4 + j][r] = vv[j] - mv[j];
        }
        if (wq == 0) x128s[r] = xb[r * 256 + 128];
    }
    __syncthreads();

    // stage 2: each wave owns 8 rows (broadcast LDS reads), each lane one ky
    const int rowg = tid >> 6;      // wave id: rows rowg*8..+8
    const int ky   = tid & 63;
    float ss, sc;
    sincosf(TWO_PI * (float)ky * (1.0f / 256.0f), &ss, &sc);
    float rc = 1.0f, rs = 0.0f;     // (cos, sin)(t*wp*ky)
    float tc[8] = {0.f}, ts[8] = {0.f};

#pragma unroll 2
    for (int wp = 0; wp < 128; ++wp) {
        float4 e0 = *(const float4*)&Et[wp][rowg * 8];
        float4 e1 = *(const float4*)&Et[wp][rowg * 8 + 4];
        float4 o0 = *(const float4*)&Ot[wp][rowg * 8];
        float4 o1 = *(const float4*)&Ot[wp][rowg * 8 + 4];
        float e[8] = {e0.x, e0.y, e0.z, e0.w, e1.x, e1.y, e1.z, e1.w};
        float o[8] = {o0.x, o0.y, o0.z, o0.w, o1.x, o1.y, o1.z, o1.w};
#pragma unroll
        for (int j = 0; j < 8; ++j) {
            tc[j] = fmaf(e[j], rc, tc[j]);
            ts[j] = fmaf(o[j], rs, ts[j]);
        }
        float nc = fmaf(rc, sc, -rs * ss);
        float ns = fmaf(rc, ss, rs * sc);
        rc = nc; rs = ns;
    }
    const float sg = (ky & 1) ? -1.0f : 1.0f;
#pragma unroll
    for (int j = 0; j < 8; ++j) tc[j] = fmaf(sg, x128s[rowg * 8 + j], tc[j]);

    float* tco = Tc_g + ((size_t)bil * 256 + hc * 32 + rowg * 8) * 64 + ky;
    float* tso = Ts_g + ((size_t)bil * 256 + hc * 32 + rowg * 8) * 64 + ky;
#pragma unroll
    for (int j = 0; j < 8; ++j) {
        tco[j * 64] = tc[j];
        tso[j * 64] = ts[j];
    }
}

// ---------------------------------------------------------------------------
// F2: block = bil. Y[kx][ky] = sum_h T[h] e^{-i t h kx} via hp/mirror pair folds.
// Main loop hp in [1,128] (hp=128 double-counted, corrected in epilogue with hp=0).
// ---------------------------------------------------------------------------
__global__ __launch_bounds__(256, 4) void f2_kernel(const float* __restrict__ Tc_g,
                                                    const float* __restrict__ Ts_g,
                                                    float2* __restrict__ Y,
                                                    int bi0) {
    const int bil = blockIdx.x;
    const int tid = threadIdx.x;
    const int kxg = tid >> 4, kyg = tid & 15;

    __shared__ float TcS[64][68];   // rows 0..31: hp slab, 32..63: mirror slab
    __shared__ float TsS[64][68];

    float stc[4], sts[4], rc[4], rs[4];
#pragma unroll
    for (int a = 0; a < 4; ++a) {
        int kx = kxg * 4 + a;
        sincosf(TWO_PI * (float)kx * (1.0f / 256.0f), &sts[a], &stc[a]);
        rc[a] = stc[a]; rs[a] = sts[a];    // at hp = 1
    }
    float yre[4][4] = {{0.f}}, yim[4][4] = {{0.f}};

    for (int c = 0; c < 4; ++c) {
        if (c) __syncthreads();
        {
            const int r = tid >> 2, q = tid & 3;
            const int grow = (r < 32) ? (c * 32 + 1 + r) : (224 - c * 32 + (r - 32));
            const float* srcalifc = Tc_g + ((size_t)bil * 256 + grow) * 64 + q * 16;
            const float* srs = Ts_g + ((size_t)bil * 256 + grow) * 64 + q * 16;
#pragma unroll
            for (int k4 = 0; k4 < 4; ++k4) {
                *(float4*)&TcS[r][q * 16 + k4 * 4] = *(const float4*)(srcalifc + k4 * 4);
                *(float4*)&TsS[r][q * 16 + k4 * 4] = *(const float4*)(srs + k4 * 4);
            }
        }
        __syncthreads();

#pragma unroll 2
        for (int j = 0; j < 32; ++j) {
            float4 th = *(const float4*)&TcS[j][kyg * 4];
            float4 tm = *(const float4*)&TcS[63 - j][kyg * 4];
            float4 sh = *(const float4*)&TsS[j][kyg * 4];
            float4 sm = *(const float4*)&TsS[63 - j][kyg * 4];
            float ce[4] = {th.x + tm.x, th.y + tm.y, th.z + tm.z, th.w + tm.w};
            float cd[4] = {th.x - tm.x, th.y - tm.y, th.z - tm.z, th.w - tm.w};
            float se[4] = {sh.x + sm.x, sh.y + sm.y, sh.z + sm.z, sh.w + sm.w};
            float sd[4] = {sh.x - sm.x, sh.y - sm.y, sh.z - sm.z, sh.w - sm.w};
#pragma unroll
            for (int a = 0; a < 4; ++a) {
#pragma unroll
                for (int cc = 0; cc < 4; ++cc) {
                    yre[a][cc] = fmaf(rc[a], ce[cc], fmaf(-rs[a], sd[cc], yre[a][cc]));
                    yim[a][cc] = fmaf(-rs[a], cd[cc], fmaf(-rc[a], se[cc], yim[a][cc]));
                }
                float nc = fmaf(rc[a], stc[a], -rs[a] * sts[a]);
                float ns = fmaf(rc[a], sts[a], rs[a] * stc[a]);
                rc[a] = nc; rs[a] = ns;
            }
        }
    }

    // epilogue: + row 0 (single), - overcount of row 128
    const size_t tb = (size_t)bil * 256 * 64 + kyg * 4;
    float4 tc0   = *(const float4*)(Tc_g + tb);
    float4 ts0   = *(const float4*)(Ts_g + tb);
    float4 tc128 = *(const float4*)(Tc_g + tb + (size_t)128 * 64);
    float4 ts128 = *(const float4*)(Ts_g + tb + (size_t)128 * 64);
    float t0c[4] = {tc0.x, tc0.y, tc0.z, tc0.w};
    float t0s[4] = {ts0.x, ts0.y, ts0.z, ts0.w};
    float t1c[4] = {tc128.x, tc128.y, tc128.z, tc128.w};
    float t1s[4] = {ts128.x, ts128.y, ts128.z, ts128.w};
#pragma unroll
    for (int a = 0; a < 4; ++a) {
        const float sg = ((kxg * 4 + a) & 1) ? -1.0f : 1.0f;
#pragma unroll
        for (int cc = 0; cc < 4; ++cc) {
            yre[a][cc] += t0c[cc] - sg * t1c[cc];
            yim[a][cc] += -t0s[cc] + sg * t1s[cc];
        }
    }

    float2* yo = Y + (size_t)(bi0 + bil) * 4096;
#pragma unroll
    for (int a = 0; a < 4; ++a) {
        int kx = kxg * 4 + a;
        *(float4*)(yo + (size_t)kx * 64 + kyg * 4) =
            make_float4(yre[a][0], yim[a][0], yre[a][1], yim[a][1]);
        *(float4*)(yo + (size_t)kx * 64 + kyg * 4 + 2) =
            make_float4(yre[a][2], yim[a][2], yre[a][3], yim[a][3]);
    }
}

// ---------------------------------------------------------------------------
// MIX: in-place (Y and Mx may alias: block stages its modes before writing).
// ---------------------------------------------------------------------------
__global__ __launch_bounds__(256) void mix_kernel(const float2* Yin,
                                                  const float* __restrict__ Wg,
                                                  float2* Mx) {
    const int kx    = blockIdx.x >> 3;
    const int kyo   = blockIdx.x & 7;
    const int tid   = threadIdx.x;
    const int kxky0 = kx * 64 + kyo * 8;

    __shared__ float2 Ys[128 * 64];      // [i][b][j]

#pragma unroll
    for (int s = 0; s < 32; ++s) {
        int n = tid + s * 256;
        int b = n >> 10, i = (n >> 3) & 127, j = n & 7;
        Ys[i * 64 + b * 8 + j] = Yin[(size_t)(b * 128 + i) * 4096 + kxky0 + j];
    }
    __syncthreads();

    const int o  = tid >> 1;
    const int jh = tid & 1;

    float accre[8][4] = {{0.f}}, accim[8][4] = {{0.f}};
    const float* wp = Wg + ((size_t)o * 4096 + kxky0 + jh * 4) * 2;
    const size_t istride = (size_t)128 * 4096 * 2;

    for (int i = 0; i < 128; ++i) {
        float4 wa = *(const float4*)(wp + (size_t)i * istride);
        float4 wb = *(const float4*)(wp + (size_t)i * istride + 4);
#pragma unroll
        for (int b = 0; b < 8; ++b) {
            float4 y01 = *(const float4*)&Ys[i * 64 + b * 8 + jh * 4];
            float4 y23 = *(const float4*)&Ys[i * 64 + b * 8 + jh * 4 + 2];
            accre[b][0] = fmaf(y01.x, wa.x, fmaf(-y01.y, wa.y, accre[b][0]));
            accim[b][0] = fmaf(y01.x, wa.y, fmaf( y01.y, wa.x, accim[b][0]));
            accre[b][1] = fmaf(y01.z, wa.z, fmaf(-y01.w, wa.w, accre[b][1]));
            accim[b][1] = fmaf(y01.z, wa.w, fmaf( y01.w, wa.z, accim[b][1]));
            accre[b][2] = fmaf(y23.x, wb.x, fmaf(-y23.y, wb.y, accre[b][2]));
            accim[b][2] = fmaf(y23.x, wb.y, fmaf( y23.y, wb.x, accim[b][2]));
            accre[b][3] = fmaf(y23.z, wb.z, fmaf(-y23.w, wb.w, accre[b][3]));
            accim[b][3] = fmaf(y23.z, wb.w, fmaf( y23.w, wb.z, accim[b][3]));
        }
    }
#pragma unroll
    for (int b = 0; b < 8; ++b) {
        float2* mo = Mx + (size_t)(b * 128 + o) * 4096 + kxky0 + jh * 4;
        *(float4*)(mo)     = make_float4(accre[b][0], accim[b][0], accre[b][1], accim[b][1]);
        *(float4*)(mo + 2) = make_float4(accre[b][2], accim[b][2], accre[b][3], accim[b][3]);
    }
}

// ---------------------------------------------------------------------------
// I1: block = (bil, hp-chunk of 32). From M, write U rows hp and 256-hp
// (scaled by s*w_ky). hp=128 tail on chunk 3.
// ---------------------------------------------------------------------------
__global__ __launch_bounds__(256, 4) void i1_kernel(const float2* __restrict__ M,
                                                    float* __restrict__ Uc_g,
                                                    float* __restrict__ Us_g,
                                                    int bi0) {
    const int bil   = blockIdx.x >> 2;
    const int chunk = blockIdx.x & 3;
    const int tid   = threadIdx.x;

    __shared__ float Mre[64][68], Mim[64][68];

    const float2* Mb = M + (size_t)(bi0 + bil) * 4096;
#pragma unroll
    for (int s = 0; s < 16; ++s) {
        int n = tid + s * 256;
        float2 v = Mb[n];
        Mre[n >> 6][n & 63] = v.x;
        Mim[n >> 6][n & 63] = v.y;
    }
    __syncthreads();

    const int hpl = tid >> 3;       // 0..31
    const int kyo = tid & 7;
    const int hp  = chunk * 32 + hpl;
    float ss, sc;
    sincosf(TWO_PI * (float)hp * (1.0f / 256.0f), &ss, &sc);
    float rc = 1.0f, rs = 0.0f;
    float A[8] = {0.f}, Bv[8] = {0.f}, C[8] = {0.f}, D[8] = {0.f};

#pragma unroll 2
    for (int kx = 0; kx < 64; ++kx) {
        float4 mr0 = *(const float4*)&Mre[kx][kyo * 8];
        float4 mr1 = *(const float4*)&Mre[kx][kyo * 8 + 4];
        float4 mi0 = *(const float4*)&Mim[kx][kyo * 8];
        float4 mi1 = *(const float4*)&Mim[kx][kyo * 8 + 4];
        float mr[8] = {mr0.x, mr0.y, mr0.z, mr0.w, mr1.x, mr1.y, mr1.z, mr1.w};
        float mi[8] = {mi0.x, mi0.y, mi0.z, mi0.w, mi1.x, mi1.y, mi1.z, mi1.w};
#pragma unroll
        for (int k = 0; k < 8; ++k) {
            A[k]  = fmaf(mr[k], rc, A[k]);
            Bv[k] = fmaf(mr[k], rs, Bv[k]);
            C[k]  = fmaf(mi[k], rc, C[k]);
            D[k]  = fmaf(mi[k], rs, D[k]);
        }
        float nc = fmaf(rc, sc, -rs * ss);
        float ns = fmaf(rc, ss, rs * sc);
        rc = nc; rs = ns;
    }

    const float s2 = 2.0f / 65536.0f;
    const int mh = (256 - hp) & 255;
    float* uch = Uc_g + ((size_t)bil * 256 + hp) * 64 + kyo * 8;
    float* ush = Us_g + ((size_t)bil * 256 + hp) * 64 + kyo * 8;
    float* ucm = Uc_g + ((size_t)bil * 256 + mh) * 64 + kyo * 8;
    float* usm = Us_g + ((size_t)bil * 256 + mh) * 64 + kyo * 8;
    float vh[8], wh[8], vm[8], wm[8];
#pragma unroll
    for (int k = 0; k < 8; ++k) {
        const float wk = ((kyo * 8 + k) == 0) ? 0.5f * s2 : s2;
        vh[k] = (A[k] - D[k]) * wk;
        wh[k] = (C[k] + Bv[k]) * wk;
        vm[k] = (A[k] + D[k]) * wk;
        wm[k] = (C[k] - Bv[k]) * wk;
    }
    *(float4*)(uch)     = make_float4(vh[0], vh[1], vh[2], vh[3]);
    *(float4*)(uch + 4) = make_float4(vh[4], vh[5], vh[6], vh[7]);
    *(float4*)(ush)     = make_float4(wh[0], wh[1], wh[2], wh[3]);
    *(float4*)(ush + 4) = make_float4(wh[4], wh[5], wh[6], wh[7]);
    *(float4*)(ucm)     = make_float4(vm[0], vm[1], vm[2], vm[3]);
    *(float4*)(ucm + 4) = make_float4(vm[4], vm[5], vm[6], vm[7]);
    *(float4*)(usm)     = make_float4(wm[0], wm[1], wm[2], wm[3]);
    *(float4*)(usm + 4) = make_float4(wm[4], wm[5], wm[6], wm[7]);

    if (chunk == 3 && tid < 64) {
        const int ky = tid;
        float a = 0.f, c2 = 0.f, sg = 1.f;
        for (int kx = 0; kx < 64; ++kx) {
            a  = fmaf(sg, Mre[kx][ky], a);
            c2 = fmaf(sg, Mim[kx][ky], c2);
            sg = -sg;
        }
        const float wk = (ky == 0) ? 0.5f * s2 : s2;
        Uc_g[((size_t)bil * 256 + 128) * 64 + ky] = a * wk;
        Us_g[((size_t)bil * 256 + 128) * 64 + ky] = c2 * wk;
    }
}

// ---------------------------------------------------------------------------
// I2: block = (bil, h-chunk of 64). out[h][wp] = Pe-Po, out[h][256-wp] = Pe+Po,
// out[h][128] from alternating sum. U staged transposed in LDS.
// ---------------------------------------------------------------------------
__global__ __launch_bounds__(256, 3) void i2_kernel(const float* __restrict__ Uc_g,
                                                    const float* __restrict__ Us_g,
                                                    float* __restrict__ out,
                                                    int bi0) {
    const int bil = blockIdx.x >> 2;
    const int hc  = blockIdx.x & 3;
    const int tid = threadIdx.x;

    __shared__ float UcT[64][68], UsT[64][68];   // [ky][h-local]

    {
        const int hl = tid >> 2, q = tid & 3;
        const float* sc_ = Uc_g + ((size_t)bil * 256 + hc * 64 + hl) * 64 + q * 16;
        const float* ss_ = Us_g + ((size_t)bil * 256 + hc * 64 + hl) * 64 + q * 16;
#pragma unroll
        for (int k4 = 0; k4 < 4; ++k4) {
            float4 a = *(const float4*)(sc_ + k4 * 4);
            float4 b = *(const float4*)(ss_ + k4 * 4);
            UcT[q * 16 + k4 * 4 + 0][hl] = a.x;
            UcT[q * 16 + k4 * 4 + 1][hl] = a.y;
            UcT[q * 16 + k4 * 4 + 2][hl] = a.z;
            UcT[q * 16 + k4 * 4 + 3][hl] = a.w;
            UsT[q * 16 + k4 * 4 + 0][hl] = b.x;
            UsT[q * 16 + k4 * 4 + 1][hl] = b.y;
            UsT[q * 16 + k4 * 4 + 2][hl] = b.z;
            UsT[q * 16 + k4 * 4 + 3][hl] = b.w;
        }
    }
    __syncthreads();

    const int hg  = tid >> 5;       // 0..7 : rows hg*8..+8
    const int wpg = tid & 31;       // wp = wpg*4..+4
    float stc[4], sts[4], rc[4], rs[4];
#pragma unroll
    for (int a = 0; a < 4; ++a) {
        sincosf(TWO_PI * (float)(wpg * 4 + a) * (1.0f / 256.0f), &sts[a], &stc[a]);
        rc[a] = 1.0f; rs[a] = 0.0f;
    }
    float pe[4][8] = {{0.f}}, po[4][8] = {{0.f}}, p128[8] = {0.f};

#pragma unroll 2
    for (int ky = 0; ky < 64; ++ky) {
        float4 u0 = *(const float4*)&UcT[ky][hg * 8];
        float4 u1 = *(const float4*)&UcT[ky][hg * 8 + 4];
        float4 v0 = *(const float4*)&UsT[ky][hg * 8];
        float4 v1 = *(const float4*)&UsT[ky][hg * 8 + 4];
        float uc[8] = {u0.x, u0.y, u0.z, u0.w, u1.x, u1.y, u1.z, u1.w};
        float us[8] = {v0.x, v0.y, v0.z, v0.w, v1.x, v1.y, v1.z, v1.w};
#pragma unroll
        for (int a = 0; a < 4; ++a) {
#pragma unroll
            for (int j = 0; j < 8; ++j) {
                pe[a][j] = fmaf(uc[j], rc[a], pe[a][j]);
                po[a][j] = fmaf(us[j], rs[a], po[a][j]);
            }
            float nc = fmaf(rc[a], stc[a], -rs[a] * sts[a]);
            float ns = fmaf(rc[a], sts[a], rs[a] * stc[a]);
            rc[a] = nc; rs[a] = ns;
        }
        const float sg = (ky & 1) ? -1.0f : 1.0f;
#pragma unroll
        for (int j = 0; j < 8; ++j) p128[j] = fmaf(sg, uc[j], p128[j]);
    }

    float* ob = out + (size_t)(bi0 + bil) * 65536 + (size_t)hc * 64 * 256;
#pragma unroll
    for (int j = 0; j < 8; ++j) {
        float* orow = ob + (size_t)(hg * 8 + j) * 256;
        *(float4*)(orow + wpg * 4) = make_float4(pe[0][j] - po[0][j], pe[1][j] - po[1][j],
                                                 pe[2][j] - po[2][j], pe[3][j] - po[3][j]);
#pragma unroll
        for (int a = 0; a < 4; ++a) {
            const int wp = wpg * 4 + a;
            if (wp) orow[256 - wp] = pe[a][j] + po[a][j];
        }
        if (wpg == 0) orow[128] = p128[j];
    }
}

// ---------------------------------------------------------------------------
extern "C" void kernel_launch(void* const* d_in, const int* in_sizes, int n_in,
                              void* d_out, int out_size, void* d_ws, size_t ws_size,
                              hipStream_t stream) {
    (void)in_sizes; (void)n_in; (void)out_size;
    const float* x  = (const float*)d_in[0];
    const float* wg = (const float*)d_in[1];
    float* outp = (float*)d_out;

    const size_t ymBytes = (size_t)1024 * 4096 * sizeof(float2);   // 33.55 MB
    int NG;                                                        // bi per group
    if      (ws_size >= (size_t)131072 * 1024 + ymBytes) NG = 1024;
    else if (ws_size >= (size_t)131072 * 512  + ymBytes) NG = 512;
    else                                                 NG = 256;

    char* base = (char*)d_ws;
    float*  Tc = (float*)base;                       // NG*256*64 floats
    float*  Ts = Tc + (size_t)NG * 16384;
    float2* YM = (float2*)(base + (size_t)NG * 131072);
    float*  Uc = Tc;                                 // reuse after F2
    float*  Us = Ts;

    const int groups = 1024 / NG;
    for (int g = 0; g < groups; ++g) {
        f1_kernel<<<NG * 8, 256, 0, stream>>>(x + (size_t)g * NG * 65536, Tc, Ts);
        f2_kernel<<<NG, 256, 0, stream>>>(Tc, Ts, YM, g * NG);
    }
    mix_kernel<<<64 * 8, 256, 0, stream>>>(YM, wg, YM);
    for (int g = 0; g < groups; ++g) {
        i1_kernel<<<NG * 4, 256, 0, stream>>>(YM, Uc, Us, g * NG);
        i2_kernel<<<NG * 4, 256, 0, stream>>>(Uc, Us, outp, g * NG);
    }
}

// Round 3
// 636.385 us; speedup vs baseline: 1.5779x; 1.0360x over previous
//
#include <hip/hip_runtime.h>
#include <cstddef>

// FNO spectral conv via MFMA (bf16 hi/lo split, fp32 accumulate).
// FA: T[bi,h,ky] (DFT along w)      : A=x rows,  B=Wfa (frag-order twiddle)
// FB: Y[bi,kx,ky] (DFT along h)     : A=T rows,  B=Wfb
// mix: per-mode complex channel GEMM (fp32 VALU, weight-BW-bound, in-place)
// IB: G[bo,h,ky] (inv DFT along kx) : A=M rows,  B=Wib
// IA: out[bo,h,w] (inv DFT along ky): A=Wia,     B=G cols  (D rows=w contiguous)
// Scratch: T in d_out (dead before IA overwrites); G chunked in d_ws.

typedef __attribute__((ext_vector_type(8))) short bf16x8;
typedef __attribute__((ext_vector_type(4))) float f32x4;
typedef unsigned short u16;

#define TWO_PI 6.28318530717958647692f
static constexpr float T256 = 6.28318530717958647692f / 256.0f;

// table offsets in 32B slots:  fa[64f] fb[128f] ib[128f] ia[64f], 64 lanes each
static constexpr int FB_OFF = 4096;      // 64*64
static constexpr int IB_OFF = 12288;     // +128*64
static constexpr int IA_OFF = 20480;     // +128*64
static constexpr int TW_SLOTS = 24576;   // *32B = 768 KB

__device__ __forceinline__ u16 f2bf(float f) {
    unsigned u = __float_as_uint(f);
    return (u16)((u + 0x7FFFu + ((u >> 16) & 1u)) >> 16);
}
__device__ __forceinline__ float bf2f(u16 h) {
    return __uint_as_float(((unsigned)h) << 16);
}
__device__ __forceinline__ void split8(const float* v, bf16x8& hi, bf16x8& lo) {
#pragma unroll
    for (int j = 0; j < 8; ++j) {
        u16 h = f2bf(v[j]);
        hi[j] = (short)h;
        lo[j] = (short)f2bf(v[j] - bf2f(h));
    }
}

// ---------------------------------------------------------------------------
// twiddle gen: one thread per (frag,lane) slot; writes [8 hi][8 lo] bf16.
// ---------------------------------------------------------------------------
__global__ __launch_bounds__(256) void gen_kernel(u16* __restrict__ tw) {
    const int t = blockIdx.x * 256 + threadIdx.x;       // 0..24575
    const int lane = t & 63, f = t >> 6;                // f: 0..383
    const int lr = lane & 15, lg = lane >> 4;
    float val[8];
#pragma unroll
    for (int j = 0; j < 8; ++j) {
        float v = 0.0f;
        if (f < 64) {                                   // FA  B[w][col], K=256,N=128
            int nf = f >> 3, ks = f & 7;
            int col = nf * 16 + lr, k = ks * 32 + lg * 8 + j;   // k = w
            int cc = (col < 64) ? col : (col - 64);
            float ss, sc; sincosf(T256 * (float)((k * cc) & 255), &ss, &sc);
            v = (col < 64) ? sc : ss;
        } else if (f < 192) {                           // FB  B[k][col], K=512,N=128
            int fid = f - 64, nf = fid >> 4, ks = fid & 15;
            int col = nf * 16 + lr, k = ks * 32 + lg * 8 + j;
            int kx = col & 63, im = col >> 6;
            int h = k & 255, part = k >> 8;             // 0=Tc, 1=Ts
            float ss, sc; sincosf(T256 * (float)((h * kx) & 255), &ss, &sc);
            if (im == 0) v = part ? -ss : sc;           // Yre: +c, -s
            else         v = part ? -sc : -ss;          // Yim: -s, -c
        } else if (f < 320) {                           // IB  B[k][col], K=128,N=512
            int fid = f - 192, nf = fid >> 2, ks = fid & 3;
            int col = nf * 16 + lr, k = ks * 32 + lg * 8 + j;
            int h = col & 255, reim = col >> 8;
            int kx = k & 63, part = k >> 6;             // 0=Mre, 1=Mim
            float ss, sc; sincosf(T256 * (float)((h * kx) & 255), &ss, &sc);
            if (reim == 0) v = part ? -ss : sc;         // Gre: +c, -s
            else           v = part ?  sc :  ss;        // Gim: +s, +c
        } else {                                        // IA  A[w][k], M=256,K=128
            int fid = f - 320, mf = fid >> 2, ks = fid & 3;
            int w = mf * 16 + lr, k = ks * 32 + lg * 8 + j;
            int ky = k & 63, part = k >> 6;             // 0=Gre, 1=Gim
            float wt = (ky ? 2.0f : 1.0f) * (1.0f / 65536.0f);
            float ss, sc; sincosf(T256 * (float)((w * ky) & 255), &ss, &sc);
            v = part ? (-wt * ss) : (wt * sc);
        }
        val[j] = v;
    }
    bf16x8 hi, lo;
    split8(val, hi, lo);
    *(bf16x8*)(tw + (size_t)t * 16)     = hi;
    *(bf16x8*)(tw + (size_t)t * 16 + 8) = lo;
}

// ---------------------------------------------------------------------------
// FA: grid = 1024 bi * 2 h-halves. Block: 128 rows x 128 cols, K=256.
// T_t[bi][ky][cs][h] bf16 hi/lo (transposed write via D-frag rows).
// ---------------------------------------------------------------------------
__global__ __launch_bounds__(256) void fa_kernel(const float* __restrict__ x,
                                                 const u16* __restrict__ tw,
                                                 u16* __restrict__ Thi,
                                                 u16* __restrict__ Tlo) {
    const int bi = blockIdx.x >> 1, hhalf = blockIdx.x & 1;
    const int lane = threadIdx.x & 63, wid = threadIdx.x >> 6;
    const int wm = wid >> 1, wn = wid & 1;
    const int lr = lane & 15, lg = lane >> 4;

    f32x4 acc[4][4] = {};
    const float* xrow[4];
#pragma unroll
    for (int mf = 0; mf < 4; ++mf) {
        int row = hhalf * 128 + wm * 64 + mf * 16 + lr;
        xrow[mf] = x + (size_t)bi * 65536 + (size_t)row * 256 + lg * 8;
    }

    for (int ks = 0; ks < 8; ++ks) {
        bf16x8 ah[4], al[4];
#pragma unroll
        for (int mf = 0; mf < 4; ++mf) {
            float v[8];
            *(float4*)v       = *(const float4*)(xrow[mf] + ks * 32);
            *(float4*)(v + 4) = *(const float4*)(xrow[mf] + ks * 32 + 4);
            split8(v, ah[mf], al[mf]);
        }
        bf16x8 bh[4], bl[4];
#pragma unroll
        for (int nf = 0; nf < 4; ++nf) {
            size_t s = ((size_t)((wn * 4 + nf) * 8 + ks) * 64 + lane) * 16;
            bh[nf] = *(const bf16x8*)(tw + s);
            bl[nf] = *(const bf16x8*)(tw + s + 8);
        }
#pragma unroll
        for (int mf = 0; mf < 4; ++mf)
#pragma unroll
            for (int nf = 0; nf < 4; ++nf) {
                acc[mf][nf] = __builtin_amdgcn_mfma_f32_16x16x32_bf16(ah[mf], bh[nf], acc[mf][nf], 0, 0, 0);
                acc[mf][nf] = __builtin_amdgcn_mfma_f32_16x16x32_bf16(ah[mf], bl[nf], acc[mf][nf], 0, 0, 0);
                acc[mf][nf] = __builtin_amdgcn_mfma_f32_16x16x32_bf16(al[mf], bh[nf], acc[mf][nf], 0, 0, 0);
            }
    }

#pragma unroll
    for (int mf = 0; mf < 4; ++mf)
#pragma unroll
        for (int nf = 0; nf < 4; ++nf) {
            int col = wn * 64 + nf * 16 + lr;
            int ky = col & 63, cs = col >> 6;
            int hh = hhalf * 128 + wm * 64 + mf * 16 + lg * 4;
            size_t o = (size_t)bi * 32768 + (size_t)ky * 512 + cs * 256 + hh;
            ushort4 h4, l4;
            float f0 = acc[mf][nf][0], f1 = acc[mf][nf][1], f2 = acc[mf][nf][2], f3 = acc[mf][nf][3];
            h4.x = f2bf(f0); h4.y = f2bf(f1); h4.z = f2bf(f2); h4.w = f2bf(f3);
            l4.x = f2bf(f0 - bf2f(h4.x)); l4.y = f2bf(f1 - bf2f(h4.y));
            l4.z = f2bf(f2 - bf2f(h4.z)); l4.w = f2bf(f3 - bf2f(h4.w));
            *(ushort4*)(Thi + o) = h4;
            *(ushort4*)(Tlo + o) = l4;
        }
}

// ---------------------------------------------------------------------------
// FB: grid = 1024 (bi). Block: 64 rows (ky) x 128 cols, K=512. Wave: 16x128.
// Epilogue LDS combine -> Y[bi][kx*64+ky] float2.
// ---------------------------------------------------------------------------
__global__ __launch_bounds__(256) void fb_kernel(const u16* __restrict__ Thi,
                                                 const u16* __restrict__ Tlo,
                                                 const u16* __restrict__ tw,
                                                 float2* __restrict__ Y) {
    const int bi = blockIdx.x;
    const int tid = threadIdx.x;
    const int lane = tid & 63, wid = tid >> 6;
    const int lr = lane & 15, lg = lane >> 4;

    f32x4 acc[8] = {};
    const size_t R = (size_t)bi * 64 + wid * 16 + lr;
    const u16* arh = Thi + R * 512 + lg * 8;
    const u16* arl = Tlo + R * 512 + lg * 8;

    for (int ks = 0; ks < 16; ++ks) {
        bf16x8 ah = *(const bf16x8*)(arh + ks * 32);
        bf16x8 al = *(const bf16x8*)(arl + ks * 32);
#pragma unroll
        for (int nf = 0; nf < 8; ++nf) {
            size_t s = ((size_t)(FB_OFF) + (size_t)(nf * 16 + ks) * 64 + lane) * 16;
            bf16x8 bh = *(const bf16x8*)(tw + s);
            bf16x8 bl = *(const bf16x8*)(tw + s + 8);
            acc[nf] = __builtin_amdgcn_mfma_f32_16x16x32_bf16(ah, bh, acc[nf], 0, 0, 0);
            acc[nf] = __builtin_amdgcn_mfma_f32_16x16x32_bf16(ah, bl, acc[nf], 0, 0, 0);
            acc[nf] = __builtin_amdgcn_mfma_f32_16x16x32_bf16(al, bh, acc[nf], 0, 0, 0);
        }
    }

    __shared__ float L[64][129];
#pragma unroll
    for (int nf = 0; nf < 8; ++nf) {
        int col = nf * 16 + lr;
        int row = wid * 16 + lg * 4;
#pragma unroll
        for (int r = 0; r < 4; ++r) L[row + r][col] = acc[nf][r];
    }
    __syncthreads();
#pragma unroll
    for (int s = 0; s < 16; ++s) {
        int n = tid + s * 256;          // 4096 = 64 kx * 64 ky
        int ky = n & 63, kx = n >> 6;
        Y[(size_t)bi * 4096 + kx * 64 + ky] = make_float2(L[ky][kx], L[ky][64 + kx]);
    }
}

// ---------------------------------------------------------------------------
// MIX: unchanged (in-place, per-block staged). Y/M live at d_out[0..33.5MB].
// ---------------------------------------------------------------------------
__global__ __launch_bounds__(256) void mix_kernel(const float2* Yin,
                                                  const float* __restrict__ Wg,
                                                  float2* Mx) {
    const int kx    = blockIdx.x >> 3;
    const int kyo   = blockIdx.x & 7;
    const int tid   = threadIdx.x;
    const int kxky0 = kx * 64 + kyo * 8;

    __shared__ float2 Ys[128 * 64];

#pragma unroll
    for (int s = 0; s < 32; ++s) {
        int n = tid + s * 256;
        int b = n >> 10, i = (n >> 3) & 127, j = n & 7;
        Ys[i * 64 + b * 8 + j] = Yin[(size_t)(b * 128 + i) * 4096 + kxky0 + j];
    }
    __syncthreads();

    const int o  = tid >> 1;
    const int jh = tid & 1;

    float accre[8][4] = {{0.f}}, accim[8][4] = {{0.f}};
    const float* wp = Wg + ((size_t)o * 4096 + kxky0 + jh * 4) * 2;
    const size_t istride = (size_t)128 * 4096 * 2;

    for (int i = 0; i < 128; ++i) {
        float4 wa = *(const float4*)(wp + (size_t)i * istride);
        float4 wb = *(const float4*)(wp + (size_t)i * istride + 4);
#pragma unroll
        for (int b = 0; b < 8; ++b) {
            float4 y01 = *(const float4*)&Ys[i * 64 + b * 8 + jh * 4];
            float4 y23 = *(const float4*)&Ys[i * 64 + b * 8 + jh * 4 + 2];
            accre[b][0] = fmaf(y01.x, wa.x, fmaf(-y01.y, wa.y, accre[b][0]));
            accim[b][0] = fmaf(y01.x, wa.y, fmaf( y01.y, wa.x, accim[b][0]));
            accre[b][1] = fmaf(y01.z, wa.z, fmaf(-y01.w, wa.w, accre[b][1]));
            accim[b][1] = fmaf(y01.z, wa.w, fmaf( y01.w, wa.z, accim[b][1]));
            accre[b][2] = fmaf(y23.x, wb.x, fmaf(-y23.y, wb.y, accre[b][2]));
            accim[b][2] = fmaf(y23.x, wb.y, fmaf( y23.y, wb.x, accim[b][2]));
            accre[b][3] = fmaf(y23.z, wb.z, fmaf(-y23.w, wb.w, accre[b][3]));
            accim[b][3] = fmaf(y23.z, wb.w, fmaf( y23.w, wb.z, accim[b][3]));
        }
    }
#pragma unroll
    for (int b = 0; b < 8; ++b) {
        float2* mo = Mx + (size_t)(b * 128 + o) * 4096 + kxky0 + jh * 4;
        *(float4*)(mo)     = make_float4(accre[b][0], accim[b][0], accre[b][1], accim[b][1]);
        *(float4*)(mo + 2) = make_float4(accre[b][2], accim[b][2], accre[b][3], accim[b][3]);
    }
}

// ---------------------------------------------------------------------------
// IB: grid = nbo*2 (bo-local, col-half). 64 rows (ky) x 256 cols, K=128.
// A staged in LDS (bf16 hi/lo) from M float2. G_t[bol][h][reim][ky] hi/lo.
// ---------------------------------------------------------------------------
__global__ __launch_bounds__(256) void ib_kernel(const float2* __restrict__ M,
                                                 const u16* __restrict__ tw,
                                                 u16* __restrict__ Ghi,
                                                 u16* __restrict__ Glo,
                                                 int bo0) {
    const int bol = blockIdx.x >> 1, ch = blockIdx.x & 1;
    const int tid = threadIdx.x;
    const int lane = tid & 63, wid = tid >> 6;
    const int lr = lane & 15, lg = lane >> 4;

    __shared__ u16 Ah[64][136], Al[64][136];

    const float2* Mb = M + (size_t)(bo0 + bol) * 4096;
#pragma unroll
    for (int s = 0; s < 16; ++s) {
        int n = tid + s * 256;
        int kx = n >> 6, ky = n & 63;
        float2 v = Mb[n];
        u16 h0 = f2bf(v.x);
        Ah[ky][kx] = h0; Al[ky][kx] = f2bf(v.x - bf2f(h0));
        u16 h1 = f2bf(v.y);
        Ah[ky][64 + kx] = h1; Al[ky][64 + kx] = f2bf(v.y - bf2f(h1));
    }
    __syncthreads();

    f32x4 acc[16] = {};
    for (int ks = 0; ks < 4; ++ks) {
        bf16x8 ah = *(const bf16x8*)(&Ah[wid * 16 + lr][ks * 32 + lg * 8]);
        bf16x8 al = *(const bf16x8*)(&Al[wid * 16 + lr][ks * 32 + lg * 8]);
#pragma unroll
        for (int nf = 0; nf < 16; ++nf) {
            size_t s = ((size_t)IB_OFF + (size_t)((ch * 16 + nf) * 4 + ks) * 64 + lane) * 16;
            bf16x8 bh = *(const bf16x8*)(tw + s);
            bf16x8 bl = *(const bf16x8*)(tw + s + 8);
            acc[nf] = __builtin_amdgcn_mfma_f32_16x16x32_bf16(ah, bh, acc[nf], 0, 0, 0);
            acc[nf] = __builtin_amdgcn_mfma_f32_16x16x32_bf16(ah, bl, acc[nf], 0, 0, 0);
            acc[nf] = __builtin_amdgcn_mfma_f32_16x16x32_bf16(al, bh, acc[nf], 0, 0, 0);
        }
    }

#pragma unroll
    for (int nf = 0; nf < 16; ++nf) {
        int h = nf * 16 + lr;
        int ky0 = wid * 16 + lg * 4;
        size_t o = (size_t)bol * 32768 + (size_t)h * 128 + ch * 64 + ky0;
        ushort4 h4, l4;
        float f0 = acc[nf][0], f1 = acc[nf][1], f2 = acc[nf][2], f3 = acc[nf][3];
        h4.x = f2bf(f0); h4.y = f2bf(f1); h4.z = f2bf(f2); h4.w = f2bf(f3);
        l4.x = f2bf(f0 - bf2f(h4.x)); l4.y = f2bf(f1 - bf2f(h4.y));
        l4.z = f2bf(f2 - bf2f(h4.z)); l4.w = f2bf(f3 - bf2f(h4.w));
        *(ushort4*)(Ghi + o) = h4;
        *(ushort4*)(Glo + o) = l4;
    }
}

// ---------------------------------------------------------------------------
// IA: grid = nbo*4 (bo-local, quadrant). Quadrant 128w x 128h, K=128.
// A = Wia (frag-order), B = G_t cols. D rows = w contiguous -> float4 stores.
// ---------------------------------------------------------------------------
__global__ __launch_bounds__(256) void ia_kernel(const u16* __restrict__ Ghi,
                                                 const u16* __restrict__ Glo,
                                                 const u16* __restrict__ tw,
                                                 float* __restrict__ out,
                                                 int bo0) {
    const int bol = blockIdx.x >> 2, q = blockIdx.x & 3;
    const int wq = q >> 1, hq = q & 1;
    const int lane = threadIdx.x & 63, wid = threadIdx.x >> 6;
    const int wm = wid >> 1, wn = wid & 1;
    const int lr = lane & 15, lg = lane >> 4;
    const int bo = bo0 + bol;

    f32x4 acc[4][4] = {};
    const u16* gb[4];
    const u16* gl[4];
#pragma unroll
    for (int nf = 0; nf < 4; ++nf) {
        int h = hq * 128 + wn * 64 + nf * 16 + lr;
        size_t o = (size_t)bol * 32768 + (size_t)h * 128 + lg * 8;
        gb[nf] = Ghi + o;
        gl[nf] = Glo + o;
    }

    for (int ks = 0; ks < 4; ++ks) {
        bf16x8 ah[4], al[4];
#pragma unroll
        for (int mf = 0; mf < 4; ++mf) {
            int mf_g = wq * 8 + wm * 4 + mf;
            size_t s = ((size_t)IA_OFF + (size_t)(mf_g * 4 + ks) * 64 + lane) * 16;
            ah[mf] = *(const bf16x8*)(tw + s);
            al[mf] = *(const bf16x8*)(tw + s + 8);
        }
        bf16x8 bh[4], bl[4];
#pragma unroll
        for (int nf = 0; nf < 4; ++nf) {
            bh[nf] = *(const bf16x8*)(gb[nf] + ks * 32);
            bl[nf] = *(const bf16x8*)(gl[nf] + ks * 32);
        }
#pragma unroll
        for (int mf = 0; mf < 4; ++mf)
#pragma unroll
            for (int nf = 0; nf < 4; ++nf) {
                acc[mf][nf] = __builtin_amdgcn_mfma_f32_16x16x32_bf16(ah[mf], bh[nf], acc[mf][nf], 0, 0, 0);
                acc[mf][nf] = __builtin_amdgcn_mfma_f32_16x16x32_bf16(ah[mf], bl[nf], acc[mf][nf], 0, 0, 0);
                acc[mf][nf] = __builtin_amdgcn_mfma_f32_16x16x32_bf16(al[mf], bh[nf], acc[mf][nf], 0, 0, 0);
            }
    }

#pragma unroll
    for (int mf = 0; mf < 4; ++mf)
#pragma unroll
        for (int nf = 0; nf < 4; ++nf) {
            int w0 = wq * 128 + wm * 64 + mf * 16 + lg * 4;
            int h  = hq * 128 + wn * 64 + nf * 16 + lr;
            *(f32x4*)(out + (size_t)bo * 65536 + (size_t)h * 256 + w0) = acc[mf][nf];
        }
}

// ---------------------------------------------------------------------------
extern "C" void kernel_launch(void* const* d_in, const int* in_sizes, int n_in,
                              void* d_out, int out_size, void* d_ws, size_t ws_size,
                              hipStream_t stream) {
    (void)in_sizes; (void)n_in; (void)out_size;
    const float* x  = (const float*)d_in[0];
    const float* wg = (const float*)d_in[1];
    float* outp = (float*)d_out;

    // d_out scratch: Y/M float2 at [0, 33.5MB); T hi/lo bf16 at [33.5MB, 167.8MB)
    float2* Y   = (float2*)d_out;
    u16*    Thi = (u16*)((char*)d_out + 33554432);
    u16*    Tlo = (u16*)((char*)d_out + 33554432 + 67108864);

    // d_ws: twiddles (768KB, padded to 1MB) + G chunk (hi/lo bf16)
    u16* tw = (u16*)d_ws;
    u16* Ghi = (u16*)((char*)d_ws + 1048576);
    size_t avail = ws_size > 1048576 ? ws_size - 1048576 : 0;
    int nbo = 1024;
    while (nbo > 64 && (size_t)nbo * 131072 > avail) nbo >>= 1;
    u16* Glo = Ghi + (size_t)nbo * 32768;

    gen_kernel<<<96, 256, 0, stream>>>(tw);
    fa_kernel<<<2048, 256, 0, stream>>>(x, tw, Thi, Tlo);
    fb_kernel<<<1024, 256, 0, stream>>>(Thi, Tlo, tw, Y);
    mix_kernel<<<512, 256, 0, stream>>>(Y, wg, Y);
    for (int bo0 = 0; bo0 < 1024; bo0 += nbo) {
        ib_kernel<<<nbo * 2, 256, 0, stream>>>(Y, tw, Ghi, Glo, bo0);
        ia_kernel<<<nbo * 4, 256, 0, stream>>>(Ghi, Glo, tw, outp, bo0);
    }
}

// Round 4
// 447.338 us; speedup vs baseline: 2.2447x; 1.4226x over previous
//
#include <hip/hip_runtime.h>
#include <cstddef>

// FNO spectral conv via MFMA (bf16 hi/lo split, fp32 accumulate), fused:
//   fwd2: per bi, 4 h-chunks: FA (x -> T-chunk in LDS) then FB accumulate -> Y
//   mix : per-mode complex channel GEMM (fp32, weight-BW-bound, in-place)
//   inv2: per (bo, h-quarter): stage M -> IB -> G in LDS -> IA -> out
// Twiddles pre-generated in MFMA fragment order (768 KB, L2-resident).

typedef __attribute__((ext_vector_type(8))) short bf16x8;
typedef __attribute__((ext_vector_type(4))) float f32x4;
typedef unsigned short u16;

static constexpr float T256 = 6.28318530717958647692f / 256.0f;
static constexpr int FB_OFF = 4096, IB_OFF = 12288, IA_OFF = 20480;

// RNE round (twiddle gen only — one-time, accuracy matters most there)
__device__ __forceinline__ u16 f2bf(float f) {
    unsigned u = __float_as_uint(f);
    return (u16)((u + 0x7FFFu + ((u >> 16) & 1u)) >> 16);
}
__device__ __forceinline__ float bf2f(u16 h) {
    return __uint_as_float(((unsigned)h) << 16);
}
__device__ __forceinline__ void split8(const float* v, bf16x8& hi, bf16x8& lo) {
#pragma unroll
    for (int j = 0; j < 8; ++j) {
        u16 h = f2bf(v[j]);
        hi[j] = (short)h;
        lo[j] = (short)f2bf(v[j] - bf2f(h));
    }
}
// cheap truncation split (4 VALU ops): hi=trunc, lo=trunc(residual)
__device__ __forceinline__ void tsplit(float f, u16& h, u16& l) {
    unsigned u = __float_as_uint(f);
    h = (u16)(u >> 16);
    float r = f - __uint_as_float(u & 0xFFFF0000u);
    l = (u16)(__float_as_uint(r) >> 16);
}
__device__ __forceinline__ void tsplit8(const float* v, bf16x8& hi, bf16x8& lo) {
#pragma unroll
    for (int j = 0; j < 8; ++j) {
        u16 h, l;
        tsplit(v[j], h, l);
        hi[j] = (short)h;
        lo[j] = (short)l;
    }
}
__device__ __forceinline__ void tsplit4(const f32x4& a, ushort4& h4, ushort4& l4) {
    tsplit(a[0], h4.x, l4.x);
    tsplit(a[1], h4.y, l4.y);
    tsplit(a[2], h4.z, l4.z);
    tsplit(a[3], h4.w, l4.w);
}

// ---------------------------------------------------------------------------
// twiddle gen (layout identical to round 3 — proven)
// ---------------------------------------------------------------------------
__global__ __launch_bounds__(256) void gen_kernel(u16* __restrict__ tw) {
    const int t = blockIdx.x * 256 + threadIdx.x;       // 0..24575
    const int lane = t & 63, f = t >> 6;
    const int lr = lane & 15, lg = lane >> 4;
    float val[8];
#pragma unroll
    for (int j = 0; j < 8; ++j) {
        float v = 0.0f;
        if (f < 64) {                                   // FA  B[w][col]
            int nf = f >> 3, ks = f & 7;
            int col = nf * 16 + lr, k = ks * 32 + lg * 8 + j;
            int cc = (col < 64) ? col : (col - 64);
            float ss, sc; sincosf(T256 * (float)((k * cc) & 255), &ss, &sc);
            v = (col < 64) ? sc : ss;
        } else if (f < 192) {                           // FB  B[k][col]
            int fid = f - 64, nf = fid >> 4, ks = fid & 15;
            int col = nf * 16 + lr, k = ks * 32 + lg * 8 + j;
            int kx = col & 63, im = col >> 6;
            int h = k & 255, part = k >> 8;
            float ss, sc; sincosf(T256 * (float)((h * kx) & 255), &ss, &sc);
            if (im == 0) v = part ? -ss : sc;
            else         v = part ? -sc : -ss;
        } else if (f < 320) {                           // IB  B[k][col]
            int fid = f - 192, nf = fid >> 2, ks = fid & 3;
            int col = nf * 16 + lr, k = ks * 32 + lg * 8 + j;
            int h = col & 255, reim = col >> 8;
            int kx = k & 63, part = k >> 6;
            float ss, sc; sincosf(T256 * (float)((h * kx) & 255), &ss, &sc);
            if (reim == 0) v = part ? -ss : sc;
            else           v = part ?  sc :  ss;
        } else {                                        // IA  A[w][k]
            int fid = f - 320, mf = fid >> 2, ks = fid & 3;
            int w = mf * 16 + lr, k = ks * 32 + lg * 8 + j;
            int ky = k & 63, part = k >> 6;
            float wt = (ky ? 2.0f : 1.0f) * (1.0f / 65536.0f);
            float ss, sc; sincosf(T256 * (float)((w * ky) & 255), &ss, &sc);
            v = part ? (-wt * ss) : (wt * sc);
        }
        val[j] = v;
    }
    bf16x8 hi, lo;
    split8(val, hi, lo);
    *(bf16x8*)(tw + (size_t)t * 16)     = hi;
    *(bf16x8*)(tw + (size_t)t * 16 + 8) = lo;
}

// ---------------------------------------------------------------------------
// fwd2: one block per bi. 4 chunks of 64 h:
//   FA: [64 h x 128 (cs,ky)], K=256(w). A from global x (trunc-split), B=twFA.
//   D -> LDS T[ky][kk], kk = cs*64 + hloc (u16 hi/lo, row pad 136 -> no conflicts)
//   FB: accumulate [64 ky x 128 (im,kx)] over this chunk's 4 k-groups.
// Epilogue: facc -> LDS f32 (aliased) -> Y[bi][kx*64+ky] float2.
// ---------------------------------------------------------------------------
__global__ __launch_bounds__(256, 2) void fwd2_kernel(const float* __restrict__ x,
                                                      const u16* __restrict__ tw,
                                                      float2* __restrict__ Y) {
    const int bi = blockIdx.x;
    const int tid = threadIdx.x;
    const int lane = tid & 63, wid = tid >> 6;
    const int lr = lane & 15, lg = lane >> 4;
    const int wm = wid >> 1, wn = wid & 1;

    __shared__ __align__(16) char smem[64 * 136 * 2 * 2];   // 34816 B
    u16 (*Th)[136] = (u16(*)[136])smem;
    u16 (*Tl)[136] = (u16(*)[136])(smem + 64 * 136 * 2);
    float (*L)[130] = (float(*)[130])smem;                  // epilogue alias

    f32x4 facc[4][2] = {};      // FB acc: [mf(ky)][nf], cols wid*32+nf*16+lr

    for (int ch = 0; ch < 4; ++ch) {
        // ---- FA chunk: h rows = ch*64 + wm*32 + mf*16 + lr ----
        f32x4 aacc[2][4] = {};
        const float* xr0 = x + (size_t)bi * 65536 + (size_t)(ch * 64 + wm * 32 + lr) * 256 + lg * 8;
        for (int ks = 0; ks < 8; ++ks) {
            bf16x8 ah[2], al[2];
#pragma unroll
            for (int mf = 0; mf < 2; ++mf) {
                const float* p = xr0 + mf * 16 * 256 + ks * 32;
                float v[8];
                *(float4*)v       = *(const float4*)p;
                *(float4*)(v + 4) = *(const float4*)(p + 4);
                tsplit8(v, ah[mf], al[mf]);
            }
#pragma unroll
            for (int nf = 0; nf < 4; ++nf) {
                size_t s = ((size_t)((wn * 4 + nf) * 8 + ks) * 64 + lane) * 16;
                bf16x8 bh = *(const bf16x8*)(tw + s);
                bf16x8 bl = *(const bf16x8*)(tw + s + 8);
#pragma unroll
                for (int mf = 0; mf < 2; ++mf) {
                    aacc[mf][nf] = __builtin_amdgcn_mfma_f32_16x16x32_bf16(ah[mf], bh, aacc[mf][nf], 0, 0, 0);
                    aacc[mf][nf] = __builtin_amdgcn_mfma_f32_16x16x32_bf16(ah[mf], bl, aacc[mf][nf], 0, 0, 0);
                    aacc[mf][nf] = __builtin_amdgcn_mfma_f32_16x16x32_bf16(al[mf], bh, aacc[mf][nf], 0, 0, 0);
                }
            }
        }
        __syncthreads();            // prev FB done reading T
#pragma unroll
        for (int mf = 0; mf < 2; ++mf)
#pragma unroll
            for (int nf = 0; nf < 4; ++nf) {
                int ky  = nf * 16 + lr;                       // D col & 63
                int kk0 = wn * 64 + wm * 32 + mf * 16 + lg * 4;
                ushort4 h4, l4;
                tsplit4(aacc[mf][nf], h4, l4);
                *(ushort4*)&Th[ky][kk0] = h4;
                *(ushort4*)&Tl[ky][kk0] = l4;
            }
        __syncthreads();

        // ---- FB accumulate over this chunk's k-groups ----
#pragma unroll
        for (int cs2 = 0; cs2 < 2; ++cs2)
#pragma unroll
            for (int hf = 0; hf < 2; ++hf) {
                const int ksg = cs2 * 8 + ch * 2 + hf;
                bf16x8 bh[2], bl[2];
#pragma unroll
                for (int nf = 0; nf < 2; ++nf) {
                    size_t s = ((size_t)FB_OFF + (size_t)((wid * 2 + nf) * 16 + ksg) * 64 + lane) * 16;
                    bh[nf] = *(const bf16x8*)(tw + s);
                    bl[nf] = *(const bf16x8*)(tw + s + 8);
                }
#pragma unroll
                for (int mf = 0; mf < 4; ++mf) {
                    bf16x8 ah = *(const bf16x8*)&Th[mf * 16 + lr][cs2 * 64 + hf * 32 + lg * 8];
                    bf16x8 al = *(const bf16x8*)&Tl[mf * 16 + lr][cs2 * 64 + hf * 32 + lg * 8];
#pragma unroll
                    for (int nf = 0; nf < 2; ++nf) {
                        facc[mf][nf] = __builtin_amdgcn_mfma_f32_16x16x32_bf16(ah, bh[nf], facc[mf][nf], 0, 0, 0);
                        facc[mf][nf] = __builtin_amdgcn_mfma_f32_16x16x32_bf16(ah, bl[nf], facc[mf][nf], 0, 0, 0);
                        facc[mf][nf] = __builtin_amdgcn_mfma_f32_16x16x32_bf16(al, bh[nf], facc[mf][nf], 0, 0, 0);
                    }
                }
            }
        __syncthreads();
    }

    // ---- epilogue: facc -> L (f32) -> Y ----
#pragma unroll
    for (int mf = 0; mf < 4; ++mf)
#pragma unroll
        for (int nf = 0; nf < 2; ++nf) {
            int col = wid * 32 + nf * 16 + lr;
            int ky0 = mf * 16 + lg * 4;
#pragma unroll
            for (int r = 0; r < 4; ++r) L[ky0 + r][col] = facc[mf][nf][r];
        }
    __syncthreads();
#pragma unroll
    for (int s = 0; s < 16; ++s) {
        int n = tid + s * 256;
        int ky = n & 63, kx = n >> 6;
        Y[(size_t)bi * 4096 + n] = make_float2(L[ky][kx], L[ky][64 + kx]);
    }
}

// ---------------------------------------------------------------------------
// MIX: unchanged (proven). In-place Y -> M with per-block staging.
// ---------------------------------------------------------------------------
__global__ __launch_bounds__(256) void mix_kernel(const float2* Yin,
                                                  const float* __restrict__ Wg,
                                                  float2* Mx) {
    const int kx    = blockIdx.x >> 3;
    const int kyo   = blockIdx.x & 7;
    const int tid   = threadIdx.x;
    const int kxky0 = kx * 64 + kyo * 8;

    __shared__ float2 Ys[128 * 64];

#pragma unroll
    for (int s = 0; s < 32; ++s) {
        int n = tid + s * 256;
        int b = n >> 10, i = (n >> 3) & 127, j = n & 7;
        Ys[i * 64 + b * 8 + j] = Yin[(size_t)(b * 128 + i) * 4096 + kxky0 + j];
    }
    __syncthreads();

    const int o  = tid >> 1;
    const int jh = tid & 1;

    float accre[8][4] = {{0.f}}, accim[8][4] = {{0.f}};
    const float* wp = Wg + ((size_t)o * 4096 + kxky0 + jh * 4) * 2;
    const size_t istride = (size_t)128 * 4096 * 2;

    for (int i = 0; i < 128; ++i) {
        float4 wa = *(const float4*)(wp + (size_t)i * istride);
        float4 wb = *(const float4*)(wp + (size_t)i * istride + 4);
#pragma unroll
        for (int b = 0; b < 8; ++b) {
            float4 y01 = *(const float4*)&Ys[i * 64 + b * 8 + jh * 4];
            float4 y23 = *(const float4*)&Ys[i * 64 + b * 8 + jh * 4 + 2];
            accre[b][0] = fmaf(y01.x, wa.x, fmaf(-y01.y, wa.y, accre[b][0]));
            accim[b][0] = fmaf(y01.x, wa.y, fmaf( y01.y, wa.x, accim[b][0]));
            accre[b][1] = fmaf(y01.z, wa.z, fmaf(-y01.w, wa.w, accre[b][1]));
            accim[b][1] = fmaf(y01.z, wa.w, fmaf( y01.w, wa.z, accim[b][1]));
            accre[b][2] = fmaf(y23.x, wb.x, fmaf(-y23.y, wb.y, accre[b][2]));
            accim[b][2] = fmaf(y23.x, wb.y, fmaf( y23.y, wb.x, accim[b][2]));
            accre[b][3] = fmaf(y23.z, wb.z, fmaf(-y23.w, wb.w, accre[b][3]));
            accim[b][3] = fmaf(y23.z, wb.w, fmaf( y23.w, wb.z, accim[b][3]));
        }
    }
#pragma unroll
    for (int b = 0; b < 8; ++b) {
        float2* mo = Mx + (size_t)(b * 128 + o) * 4096 + kxky0 + jh * 4;
        *(float4*)(mo)     = make_float4(accre[b][0], accim[b][0], accre[b][1], accim[b][1]);
        *(float4*)(mo + 2) = make_float4(accre[b][2], accim[b][2], accre[b][3], accim[b][3]);
    }
}

// ---------------------------------------------------------------------------
// inv2: one block per (bo, h-quarter hq).
//   stage M -> LDS A[ky][k] (hi/lo, trunc-split)
//   IB: [64 ky x 128 (reim,hloc)] K=128 -> D-frags -> LDS G[hloc][reim*64+ky]
//   IA: [256 w x 64 hloc] K=128, A=twIA, B=G -> out[bo][hq*64+hloc][w]
// ---------------------------------------------------------------------------
__global__ __launch_bounds__(256, 2) void inv2_kernel(const float2* __restrict__ M,
                                                      const u16* __restrict__ tw,
                                                      float* __restrict__ out) {
    const int bo = blockIdx.x >> 2, hq = blockIdx.x & 3;
    const int tid = threadIdx.x;
    const int lane = tid & 63, wid = tid >> 6;
    const int lr = lane & 15, lg = lane >> 4;

    __shared__ u16 Ah[64][136], Al[64][136];
    __shared__ u16 Gh[64][136], Gl[64][136];

    const float2* Mb = M + (size_t)bo * 4096;
#pragma unroll
    for (int s = 0; s < 16; ++s) {
        int n = tid + s * 256;
        float2 v = Mb[n];
        int kx = n >> 6, ky = n & 63;
        u16 h, l;
        tsplit(v.x, h, l); Ah[ky][kx] = h;      Al[ky][kx] = l;
        tsplit(v.y, h, l); Ah[ky][64 + kx] = h; Al[ky][64 + kx] = l;
    }
    __syncthreads();

    // ---- IB ----
    {
        const int reim = wid >> 1, csub = wid & 1;
        f32x4 bacc[4][2] = {};
        for (int ks = 0; ks < 4; ++ks) {
            bf16x8 bh[2], bl[2];
#pragma unroll
            for (int nf = 0; nf < 2; ++nf) {
                int nf_g = reim * 16 + hq * 4 + csub * 2 + nf;
                size_t s = ((size_t)IB_OFF + (size_t)(nf_g * 4 + ks) * 64 + lane) * 16;
                bh[nf] = *(const bf16x8*)(tw + s);
                bl[nf] = *(const bf16x8*)(tw + s + 8);
            }
#pragma unroll
            for (int mf = 0; mf < 4; ++mf) {
                bf16x8 ah = *(const bf16x8*)&Ah[mf * 16 + lr][ks * 32 + lg * 8];
                bf16x8 al = *(const bf16x8*)&Al[mf * 16 + lr][ks * 32 + lg * 8];
#pragma unroll
                for (int nf = 0; nf < 2; ++nf) {
                    bacc[mf][nf] = __builtin_amdgcn_mfma_f32_16x16x32_bf16(ah, bh[nf], bacc[mf][nf], 0, 0, 0);
                    bacc[mf][nf] = __builtin_amdgcn_mfma_f32_16x16x32_bf16(ah, bl[nf], bacc[mf][nf], 0, 0, 0);
                    bacc[mf][nf] = __builtin_amdgcn_mfma_f32_16x16x32_bf16(al, bh[nf], bacc[mf][nf], 0, 0, 0);
                }
            }
        }
        // D[ky][col]: col = wid*32+nf*16+lr -> (reim, hloc = csub*32+nf*16+lr)
#pragma unroll
        for (int mf = 0; mf < 4; ++mf)
#pragma unroll
            for (int nf = 0; nf < 2; ++nf) {
                int hloc = csub * 32 + nf * 16 + lr;
                int kk   = reim * 64 + mf * 16 + lg * 4;
                ushort4 h4, l4;
                tsplit4(bacc[mf][nf], h4, l4);
                *(ushort4*)&Gh[hloc][kk] = h4;
                *(ushort4*)&Gl[hloc][kk] = l4;
            }
    }
    __syncthreads();

    // ---- IA ----
    {
        f32x4 cacc[4][4] = {};
        for (int ks = 0; ks < 4; ++ks) {
            bf16x8 ah[4], al[4];
#pragma unroll
            for (int mf = 0; mf < 4; ++mf) {
                int mf_g = wid * 4 + mf;
                size_t s = ((size_t)IA_OFF + (size_t)(mf_g * 4 + ks) * 64 + lane) * 16;
                ah[mf] = *(const bf16x8*)(tw + s);
                al[mf] = *(const bf16x8*)(tw + s + 8);
            }
#pragma unroll
            for (int nf = 0; nf < 4; ++nf) {
                bf16x8 bh = *(const bf16x8*)&Gh[nf * 16 + lr][ks * 32 + lg * 8];
                bf16x8 bl = *(const bf16x8*)&Gl[nf * 16 + lr][ks * 32 + lg * 8];
#pragma unroll
                for (int mf = 0; mf < 4; ++mf) {
                    cacc[mf][nf] = __builtin_amdgcn_mfma_f32_16x16x32_bf16(ah[mf], bh, cacc[mf][nf], 0, 0, 0);
                    cacc[mf][nf] = __builtin_amdgcn_mfma_f32_16x16x32_bf16(ah[mf], bl, cacc[mf][nf], 0, 0, 0);
                    cacc[mf][nf] = __builtin_amdgcn_mfma_f32_16x16x32_bf16(al[mf], bh, cacc[mf][nf], 0, 0, 0);
                }
            }
        }
#pragma unroll
        for (int mf = 0; mf < 4; ++mf)
#pragma unroll
            for (int nf = 0; nf < 4; ++nf) {
                int w0 = wid * 64 + mf * 16 + lg * 4;
                int h  = hq * 64 + nf * 16 + lr;
                *(f32x4*)(out + (size_t)bo * 65536 + (size_t)h * 256 + w0) = cacc[mf][nf];
            }
    }
}

// ---------------------------------------------------------------------------
extern "C" void kernel_launch(void* const* d_in, const int* in_sizes, int n_in,
                              void* d_out, int out_size, void* d_ws, size_t ws_size,
                              hipStream_t stream) {
    (void)in_sizes; (void)n_in; (void)out_size; (void)ws_size;
    const float* x  = (const float*)d_in[0];
    const float* wg = (const float*)d_in[1];
    float* outp = (float*)d_out;

    u16*    tw = (u16*)d_ws;                             // 768 KB (pad to 1 MB)
    float2* Y  = (float2*)((char*)d_ws + 1048576);       // 33.5 MB

    gen_kernel<<<96, 256, 0, stream>>>(tw);
    fwd2_kernel<<<1024, 256, 0, stream>>>(x, tw, Y);
    mix_kernel<<<512, 256, 0, stream>>>(Y, wg, Y);
    inv2_kernel<<<4096, 256, 0, stream>>>(Y, tw, outp);
}